// Round 7
// baseline (95.722 us; speedup 1.0000x reference)
//
#include <hip/hip_runtime.h>

#define HH 4096
#define WW 4096

typedef float v4f __attribute__((ext_vector_type(4)));

__device__ __forceinline__ float fast_tanh(float x) {
    // tanh(x) = 1 - 2/(exp(2x)+1); saturates correctly for |x| large.
    float e = __expf(2.0f * x);
    return 1.0f - 2.0f * __builtin_amdgcn_rcpf(e + 1.0f);
}

__global__ __launch_bounds__(256) void bio_kernel(
    const float* __restrict__ v,
    const float* __restrict__ na,
    const float* __restrict__ kk,
    const float* __restrict__ ca,
    float* __restrict__ out)
{
    // XCD-bijective swizzle (grid = 8192, divisible by 8): each XCD owns a
    // contiguous band of rows so vertical stencil neighbors hit its own L2.
    int bid   = blockIdx.x;
    int chunk = gridDim.x >> 3;
    int lb    = (bid & 7) * chunk + (bid >> 3);
    int tid   = lb * 256 + (int)threadIdx.x;     // 2M threads

    // Each thread: two float4 segments in the SAME row, half a row apart.
    // Every VMEM instruction keeps a contiguous 64x16B wave footprint.
    int r  = tid >> 9;          // row, 0..4095   (512 threads per row)
    int s  = tid & 511;         // quarter index of segment A
    int cA = s * 4;             // col of segment A: 0..2044
    int cB = cA + 2048;         // col of segment B: 2048..4092
    int baseA = r * WW + cA;
    int baseB = baseA + 2048;

    int rup = (r == 0)      ? 1      : r - 1;    // reflect (exclude edge)
    int rdn = (r == HH - 1) ? HH - 2 : r + 1;
    int dup = (rup - r) * WW;
    int ddn = (rdn - r) * WW;

    // voltage: cached (stencil halo is the only reused data)
    v4f vcA = *(const v4f*)(v + baseA);
    v4f vcB = *(const v4f*)(v + baseB);
    v4f vuA = *(const v4f*)(v + baseA + dup);
    v4f vuB = *(const v4f*)(v + baseB + dup);
    v4f vdA = *(const v4f*)(v + baseA + ddn);
    v4f vdB = *(const v4f*)(v + baseB + ddn);

    // single-use streams: non-temporal, keep L2/L3 for voltage
    v4f naA = __builtin_nontemporal_load((const v4f*)(na + baseA));
    v4f naB = __builtin_nontemporal_load((const v4f*)(na + baseB));
    v4f kA  = __builtin_nontemporal_load((const v4f*)(kk + baseA));
    v4f kB  = __builtin_nontemporal_load((const v4f*)(kk + baseB));
    v4f caA = __builtin_nontemporal_load((const v4f*)(ca + baseA));
    v4f caB = __builtin_nontemporal_load((const v4f*)(ca + baseB));

    // horizontal neighbors via cross-lane shuffle (per segment); a wave's 64
    // lanes cover 256 contiguous floats of one row per segment (no straddle:
    // 512 threads/row, waves aligned).
    int lane = (int)threadIdx.x & 63;
    float vlA = __shfl_up(vcA.w, 1);
    float vrA = __shfl_down(vcA.x, 1);
    float vlB = __shfl_up(vcB.w, 1);
    float vrB = __shfl_down(vcB.x, 1);
    if (lane == 0) {
        vlA = (cA == 0) ? vcA.y : v[baseA - 1];   // reflect: col 1
        vlB = v[baseB - 1];                        // cB >= 2048, never col 0
    }
    if (lane == 63) {
        vrA = v[baseA + 4];                        // cA+4 <= 2048, never col W
        vrB = (cB + 4 == WW) ? vcB.z : v[baseB + 4];   // reflect: col W-2
    }

    const int HW = HH * WW;

#pragma unroll
    for (int seg = 0; seg < 2; ++seg) {
        v4f vc  = seg ? vcB : vcA;
        v4f vup = seg ? vuB : vuA;
        v4f vdn = seg ? vdB : vdA;
        v4f nav = seg ? naB : naA;
        v4f kv  = seg ? kB  : kA;
        v4f cav = seg ? caB : caA;
        float vl = seg ? vlB : vlA;
        float vr = seg ? vrB : vrA;
        int base = seg ? baseB : baseA;

        float cv[4]  = {vc.x,  vc.y,  vc.z,  vc.w};
        float uu[4]  = {vup.x, vup.y, vup.z, vup.w};
        float dd[4]  = {vdn.x, vdn.y, vdn.z, vdn.w};
        float lf[4]  = {vl,    vc.x,  vc.y,  vc.z};
        float rt[4]  = {vc.y,  vc.z,  vc.w,  vr};
        float nai[4] = {nav.x, nav.y, nav.z, nav.w};
        float ki[4]  = {kv.x,  kv.y,  kv.z,  kv.w};
        float cai[4] = {cav.x, cav.y, cav.z, cav.w};

        float o0[4], o1[4], o2[4], o3[4];
#pragma unroll
        for (int i = 0; i < 4; ++i) {
            float lap  = uu[i] + dd[i] + lf[i] + rt[i] - 4.0f * cv[i];
            float vupd = 0.5f * lap + 0.1f * nai[i] - 0.05f * ki[i] + 0.08f * cai[i];
            float nv   = fast_tanh(cv[i] + 0.1f * vupd);
            o0[i] = nv;
            o1[i] = nai[i] * 0.95f + 0.05f * fmaxf(nv, 0.0f);
            o2[i] = ki[i]  * 0.95f + 0.05f * fmaxf(-nv, 0.0f);
            o3[i] = cai[i] * 0.95f + 0.05f * fabsf(nv);
        }

        __builtin_nontemporal_store((v4f){o0[0],o0[1],o0[2],o0[3]}, (v4f*)(out + base));
        __builtin_nontemporal_store((v4f){o1[0],o1[1],o1[2],o1[3]}, (v4f*)(out + HW + base));
        __builtin_nontemporal_store((v4f){o2[0],o2[1],o2[2],o2[3]}, (v4f*)(out + 2*HW + base));
        __builtin_nontemporal_store((v4f){o3[0],o3[1],o3[2],o3[3]}, (v4f*)(out + 3*HW + base));
    }
}

extern "C" void kernel_launch(void* const* d_in, const int* in_sizes, int n_in,
                              void* d_out, int out_size, void* d_ws, size_t ws_size,
                              hipStream_t stream) {
    const float* v  = (const float*)d_in[0];
    const float* na = (const float*)d_in[1];
    const float* kk = (const float*)d_in[2];
    const float* ca = (const float*)d_in[3];
    float* out = (float*)d_out;

    int total = HH * (WW / 8);           // 2M threads, 2x4 cols each
    int block = 256;
    int grid  = (total + block - 1) / block;   // 8192, divisible by 8
    bio_kernel<<<grid, block, 0, stream>>>(v, na, kk, ca, out);
}

// Round 8
// 94.479 us; speedup vs baseline: 1.0132x; 1.0132x over previous
//
#include <hip/hip_runtime.h>

#define HH 4096
#define WW 4096

typedef float v4f __attribute__((ext_vector_type(4)));

__device__ __forceinline__ float fast_tanh(float x) {
    // tanh(x) = 1 - 2/(exp(2x)+1); saturates correctly for |x| large.
    float e = __expf(2.0f * x);
    return 1.0f - 2.0f * __builtin_amdgcn_rcpf(e + 1.0f);
}

__global__ __launch_bounds__(256) void bio_kernel(
    const float* __restrict__ v,
    const float* __restrict__ na,
    const float* __restrict__ kk,
    const float* __restrict__ ca,
    float* __restrict__ out)
{
    // XCD-bijective swizzle: gridDim.x = 16384 (divisible by 8). Hardware
    // round-robins physical block id across 8 XCDs; remap so each XCD owns a
    // contiguous band of 2048 blocks (= 512 rows). Vertical stencil neighbors
    // (+-4 block ids) then stay in the SAME XCD's L2 instead of being served
    // cross-XCD via L3/fabric.  [A/B r4->r6: 94.9 -> 90.0 us]
    int bid   = blockIdx.x;
    int chunk = gridDim.x >> 3;                 // 2048
    int lb    = (bid & 7) * chunk + (bid >> 3); // bijective since grid % 8 == 0
    int tid   = lb * 256 + (int)threadIdx.x;    // 4M threads

    int r  = tid >> 10;        // row, 0..4095  (1024 float4-quarters/row)
    int c4 = tid & 1023;
    int c  = c4 * 4;
    int base = r * WW + c;

    // reflect padding (mirror excluding edge)
    int rup = (r == 0)      ? 1      : r - 1;
    int rdn = (r == HH - 1) ? HH - 2 : r + 1;

    // voltage: cached loads (stencil halo is the only reused data)
    v4f vc = *(const v4f*)(v + base);
    v4f vu = *(const v4f*)(v + rup * WW + c);
    v4f vd = *(const v4f*)(v + rdn * WW + c);

    // single-use streams: non-temporal loads, keep L2/L3 for voltage
    // [A/B r2->r3: 118.6 -> 100.8 us together with NT stores]
    v4f na4 = __builtin_nontemporal_load((const v4f*)(na + base));
    v4f k4  = __builtin_nontemporal_load((const v4f*)(kk + base));
    v4f ca4 = __builtin_nontemporal_load((const v4f*)(ca + base));

    // left/right neighbors via cross-lane shuffle instead of extra loads:
    // a wave's 64 lanes cover 256 contiguous floats of ONE row.
    // [A/B r3->r4: 100.8 -> 94.9 us]
    float vl = __shfl_up(vc.w, 1);    // lane i <- lane i-1's last element
    float vr = __shfl_down(vc.x, 1);  // lane i <- lane i+1's first element
    int lane = (int)threadIdx.x & 63;
    if (lane == 0)  vl = (c == 0)      ? vc.y : v[base - 1];   // reflect: col 1
    if (lane == 63) vr = (c + 4 == WW) ? vc.z : v[base + 4];   // reflect: col W-2

    float cv[4]  = {vc.x, vc.y, vc.z, vc.w};
    float uu[4]  = {vu.x, vu.y, vu.z, vu.w};
    float dd[4]  = {vd.x, vd.y, vd.z, vd.w};
    float lf[4]  = {vl,   vc.x, vc.y, vc.z};
    float rt[4]  = {vc.y, vc.z, vc.w, vr};
    float nai[4] = {na4.x, na4.y, na4.z, na4.w};
    float ki[4]  = {k4.x,  k4.y,  k4.z,  k4.w};
    float cai[4] = {ca4.x, ca4.y, ca4.z, ca4.w};

    float o0[4], o1[4], o2[4], o3[4];
#pragma unroll
    for (int i = 0; i < 4; ++i) {
        float lap  = uu[i] + dd[i] + lf[i] + rt[i] - 4.0f * cv[i];
        float vupd = 0.5f * lap + 0.1f * nai[i] - 0.05f * ki[i] + 0.08f * cai[i];
        float nv   = fast_tanh(cv[i] + 0.1f * vupd);
        o0[i] = nv;
        o1[i] = nai[i] * 0.95f + 0.05f * fmaxf(nv, 0.0f);
        o2[i] = ki[i]  * 0.95f + 0.05f * fmaxf(-nv, 0.0f);
        o3[i] = cai[i] * 0.95f + 0.05f * fabsf(nv);
    }
    v4f ov  = (v4f){o0[0], o0[1], o0[2], o0[3]};
    v4f ona = (v4f){o1[0], o1[1], o1[2], o1[3]};
    v4f okk = (v4f){o2[0], o2[1], o2[2], o2[3]};
    v4f oca = (v4f){o3[0], o3[1], o3[2], o3[3]};

    const int HW = HH * WW;
    // streaming outputs: non-temporal, don't pollute L2/L3
    __builtin_nontemporal_store(ov,  (v4f*)(out + base));
    __builtin_nontemporal_store(ona, (v4f*)(out + HW + base));
    __builtin_nontemporal_store(okk, (v4f*)(out + 2 * HW + base));
    __builtin_nontemporal_store(oca, (v4f*)(out + 3 * HW + base));
}

extern "C" void kernel_launch(void* const* d_in, const int* in_sizes, int n_in,
                              void* d_out, int out_size, void* d_ws, size_t ws_size,
                              hipStream_t stream) {
    const float* v  = (const float*)d_in[0];
    const float* na = (const float*)d_in[1];
    const float* kk = (const float*)d_in[2];
    const float* ca = (const float*)d_in[3];
    float* out = (float*)d_out;

    int total = HH * (WW / 4);           // 4M threads, 4 cols each
    int block = 256;
    int grid  = (total + block - 1) / block;   // 16384, divisible by 8
    bio_kernel<<<grid, block, 0, stream>>>(v, na, kk, ca, out);
}